// Round 6
// baseline (214.518 us; speedup 1.0000x reference)
//
#include <hip/hip_runtime.h>

// GatedCrossModalAttention: B=16384, NM=5, D=256, H=8. FP32 I/O, bf16 internal.
// Attention collapses (Lq=Lk=1 => softmax==1):
//   branch_s(x) = x[:,mod_s] @ (Wo_s@Wv_s)^T + (Wo_s@bv_s+bo_s).
// K1: fuse weights -> WT bf16 in MFMA-fragment order, BF f32 [5][256]. ws 660 KB ONLY
//   (Round-2 lesson: big ws corrupted inputs).
// Round-3 lesson: occupancy alone bought -8%; limiter is the per-block serial chain.
// Round-4 lesson: MFMA-layout epilogue -> scattered global I/O -> 2x traffic -> 2x slower.
//   LDS park IS the layout converter. KEEP IT.
// Round-5 lesson: per-iteration-barrier structure at 1024x16 blocks thrashed caches.
// Round-6 lesson: T14 1-deep prefetch neutral — loads still drain within the same
//   barrier pair.
// Round-7 lesson: WT fragment-coalescing neutral. With R6: NO loop-body detail
//   matters — the kernel is concurrency-starved (bursty 32KB stage per 37K-cycle
//   iteration -> 910 GB/s effective, Little's law).
// Round-8 (this): hoist ALL HBM out of the loop. Prologue stages all 5 modal
//   tiles (one big burst, gate math overlaps the latency), loop runs pure
//   LDS/L2+MFMA. 16 rows/block, 256 thr, grid 1024; Axl[5] 42KB; Y parked IN
//   PLACE over the consumed A buffer (extra barrier instead of separate Yb);
//   gW read from global (L2). 3 blocks/CU. x read exactly once per block.

typedef __attribute__((ext_vector_type(8))) short short8;
typedef __attribute__((ext_vector_type(4))) float floatx4;

__device__ __forceinline__ float b2f(unsigned short h) {
    union { unsigned int u; float f; } v; v.u = ((unsigned int)h) << 16; return v.f;
}
__device__ __forceinline__ unsigned short f2b(float f) {
    union { unsigned int u; float f; } v; v.f = f;
    unsigned int u = v.u;
    return (unsigned short)((u + 0x7FFFu + ((u >> 16) & 1u)) >> 16);
}

// ---------------- K1: weight fusion ----------------
// grid (64, 5), block 256. Each block: 4 output rows (n = i0..i0+3) of one branch.
// Thread tid holds k=tid; computes WF[n][k] and scatters into WT fragment order:
//   WT[s][kk][w][ct][q4][l16][e] = WF[w*32+ct*16+l16][kk*32+q4*8+e]
__global__ __launch_bounds__(256) void k_fuse(
    const float* __restrict__ sWi, const float* __restrict__ sbi,
    const float* __restrict__ sWo, const float* __restrict__ sbo,
    const float* __restrict__ cWi, const float* __restrict__ cbi,
    const float* __restrict__ cWo, const float* __restrict__ cbo,
    unsigned short* __restrict__ WT, float* __restrict__ BF)
{
    int s = blockIdx.y;
    int i0 = blockIdx.x * 4;
    int tid = threadIdx.x;
    const float *Wo, *Wv, *bv, *bo;
    if (s == 0) { Wo = sWo; Wv = sWi + 512 * 256; bv = sbi + 512; bo = sbo; }
    else {
        int n = s - 1;
        Wo = cWo + n * 65536;
        Wv = cWi + n * 768 * 256 + 512 * 256;
        bv = cbi + n * 768 + 512;
        bo = cbo + n * 256;
    }
    __shared__ float wo[4 * 256];
    #pragma unroll
    for (int it = 0; it < 4; ++it) {
        int idx = tid + it * 256;
        wo[idx] = Wo[i0 * 256 + idx];
    }
    __syncthreads();
    float a0 = 0.f, a1 = 0.f, a2 = 0.f, a3 = 0.f;
    #pragma unroll 8
    for (int k = 0; k < 256; ++k) {
        float wv = Wv[k * 256 + tid];
        a0 += wo[k] * wv;
        a1 += wo[256 + k] * wv;
        a2 += wo[512 + k] * wv;
        a3 += wo[768 + k] * wv;
    }
    // scatter into WT fragment order
    {
        unsigned short vals[4] = { f2b(a0), f2b(a1), f2b(a2), f2b(a3) };
        int kk = tid >> 5, q4k = (tid >> 3) & 3, e = tid & 7;
        #pragma unroll
        for (int r = 0; r < 4; ++r) {
            int n = i0 + r;
            int w = n >> 5, ct = (n >> 4) & 1, l16n = n & 15;
            size_t idx = (((((((size_t)s * 8 + kk) * 8 + w) * 2 + ct) * 4 + q4k) * 16 + l16n) * 8) + e;
            WT[idx] = vals[r];
        }
    }
    // bias: one wave per output row (parallel), lane l covers k=4l..4l+3
    {
        int wv_ = tid >> 6, ln = tid & 63;
        float p = 0.f;
        #pragma unroll
        for (int u = 0; u < 4; ++u) {
            int k = ln * 4 + u;
            p += wo[wv_ * 256 + k] * bv[k];
        }
        #pragma unroll
        for (int o = 32; o > 0; o >>= 1) p += __shfl_xor(p, o, 64);
        if (ln == 0) BF[s * 256 + i0 + wv_] = p + bo[i0 + wv_];
    }
}

// ---------------- K2: fused GEMM + epilogue ----------------
__device__ __forceinline__ float wred(float v) {
    #pragma unroll
    for (int o = 32; o > 0; o >>= 1) v += __shfl_xor(v, o, 64);
    return v;
}

#define ASTR 264   // shorts; 528B row stride

// grid 1024, block 256 (4 waves). Block: rows [b0, b0+16). Wave w: GEMM cols
// [w*64, w*64+64) (ct=0..3), epilogue rows [w*4, w*4+4), lane j = lane*4.
__global__ __launch_bounds__(256, 3) void k_main(
    const float* __restrict__ x, const unsigned short* __restrict__ WT,
    const float* __restrict__ BF,
    const float* __restrict__ cln_g, const float* __restrict__ cln_b,
    const float* __restrict__ gln_g, const float* __restrict__ gln_b,
    const float* __restrict__ gW, const float* __restrict__ gb,
    const float* __restrict__ fln_g, const float* __restrict__ fln_b,
    const int* __restrict__ midx, float* __restrict__ out)
{
    __shared__ __align__(16) unsigned short Axl[5][16 * ASTR]; // 5 branch A-tiles; Y parks in place
    __shared__ float gLDS[16 * 8];                              // gates per row

    const int m = midx[0];
    const int b0 = blockIdx.x * 16;
    const int tid = threadIdx.x;
    const int wave = tid >> 6, lane = tid & 63;
    const int l16 = lane & 15, q4 = lane >> 4;
    const int j = lane * 4;

    // ---- prologue: issue ALL modal stage loads (one burst; 20 float4/thread) ----
    float4 sreg[5][4];
    #pragma unroll
    for (int mi = 0; mi < 5; ++mi) {
        int mod = (mi == 0) ? m : ((mi - 1 < m) ? mi - 1 : mi);
        #pragma unroll
        for (int it = 0; it < 4; ++it) {
            int c = tid + it * 256;             // 16 rows x 64 float4
            sreg[mi][it] = *(const float4*)(x + ((size_t)(b0 + (c >> 6)) * 5 + mod) * 256 + ((c & 63) << 2));
        }
    }

    // q rows (fp32, registers, for residuals): 4 rows per wave
    float qv[4][4];
    #pragma unroll
    for (int rr = 0; rr < 4; ++rr) {
        int r = wave * 4 + rr;
        float4 u = *(const float4*)(x + ((size_t)(b0 + r) * 5 + m) * 256 + j);
        qv[rr][0] = u.x; qv[rr][1] = u.y; qv[rr][2] = u.z; qv[rr][3] = u.w;
    }
    float4 glg = *(const float4*)(gln_g + j);
    float4 glb = *(const float4*)(gln_b + j);
    float gbv[5];
    #pragma unroll
    for (int n = 0; n < 5; ++n) gbv[n] = gb[n];

    // ---- gates (overlaps the stage-load latency; gW from global, L2-resident) ----
    #pragma unroll
    for (int rr = 0; rr < 4; ++rr) {
        int r = wave * 4 + rr;
        float s1 = wred(qv[rr][0] + qv[rr][1] + qv[rr][2] + qv[rr][3]);
        float s2 = wred(qv[rr][0]*qv[rr][0] + qv[rr][1]*qv[rr][1] +
                        qv[rr][2]*qv[rr][2] + qv[rr][3]*qv[rr][3]);
        float mn = s1 * (1.f / 256.f);
        float vr = s2 * (1.f / 256.f) - mn * mn;
        float rs = rsqrtf(vr + 1e-5f);
        float qln[4];
        qln[0] = (qv[rr][0] - mn) * rs * glg.x + glb.x;
        qln[1] = (qv[rr][1] - mn) * rs * glg.y + glb.y;
        qln[2] = (qv[rr][2] - mn) * rs * glg.z + glb.z;
        qln[3] = (qv[rr][3] - mn) * rs * glg.w + glb.w;
        float g[5];
        #pragma unroll
        for (int n = 0; n < 5; ++n) {
            float4 w4 = *(const float4*)(gW + n * 256 + j);
            float p = qln[0] * w4.x + qln[1] * w4.y + qln[2] * w4.z + qln[3] * w4.w;
            g[n] = wred(p) + gbv[n];
        }
        float mx = g[0];
        #pragma unroll
        for (int n = 1; n < 5; ++n) mx = fmaxf(mx, g[n]);
        float es = 0.f;
        #pragma unroll
        for (int n = 0; n < 5; ++n) { g[n] = __expf(g[n] - mx); es += g[n]; }
        float inv = 1.f / es;
        if (lane == 0) {
            #pragma unroll
            for (int n = 0; n < 5; ++n) gLDS[r * 8 + n] = g[n] * inv;
        }
    }

    // ---- write all staged tiles to LDS (bf16) ----
    #pragma unroll
    for (int mi = 0; mi < 5; ++mi) {
        #pragma unroll
        for (int it = 0; it < 4; ++it) {
            int c = tid + it * 256;
            float4 v = sreg[mi][it];
            uint2 p;
            p.x = (unsigned int)f2b(v.x) | ((unsigned int)f2b(v.y) << 16);
            p.y = (unsigned int)f2b(v.z) | ((unsigned int)f2b(v.w) << 16);
            *(uint2*)(&Axl[mi][(c >> 6) * ASTR + ((c & 63) << 2)]) = p;
        }
    }
    __syncthreads();  // all A-tiles + gLDS ready; NO HBM inside the loop from here

    float comb[4][4];
    #pragma unroll
    for (int rr = 0; rr < 4; ++rr)
        #pragma unroll
        for (int i = 0; i < 4; ++i) comb[rr][i] = 0.f;

    for (int s = 0; s < 5; ++s) {
        float4 bfv = *(const float4*)(BF + s * 256 + j);
        float4 cg, cb;
        if (s > 0) {
            cg = *(const float4*)(cln_g + (s - 1) * 256 + j);
            cb = *(const float4*)(cln_b + (s - 1) * 256 + j);
        }

        // GEMM: 16x256 = A(16x256) @ WF_s^T ; wave covers 64 cols (ct=0..3).
        // B loads from WT fragment order: lane L reads byte offset L*16 -> coalesced.
        floatx4 acc[4];
        #pragma unroll
        for (int ct = 0; ct < 4; ++ct) acc[ct] = (floatx4){0.f, 0.f, 0.f, 0.f};
        const unsigned short* wT = WT + (size_t)s * 65536;
        const unsigned short* As = &Axl[s][0];
        #pragma unroll
        for (int h = 0; h < 4; ++h) {
            short8 bb[8];
            #pragma unroll
            for (int kk2 = 0; kk2 < 2; ++kk2) {
                int kkg = h * 2 + kk2;
                #pragma unroll
                for (int ct = 0; ct < 4; ++ct) {
                    int wp = wave * 2 + (ct >> 1), ctp = ct & 1;
                    bb[kk2 * 4 + ct] = *(const short8*)(
                        wT + (((((size_t)kkg * 8 + wp) * 2 + ctp) * 4 + q4) * 16 + l16) * 8);
                }
            }
            #pragma unroll
            for (int kk2 = 0; kk2 < 2; ++kk2) {
                int k = (h * 2 + kk2) * 32 + q4 * 8;
                short8 a = *(const short8*)(&As[l16 * ASTR + k]);
                #pragma unroll
                for (int ct = 0; ct < 4; ++ct)
                    acc[ct] = __builtin_amdgcn_mfma_f32_16x16x32_bf16(a, bb[kk2 * 4 + ct], acc[ct], 0, 0, 0);
            }
        }
        __syncthreads();  // B_a: all waves done READING Axl[s]

        // park Y in place over Axl[s] (MFMA C-layout -> row-major, bf16)
        #pragma unroll
        for (int i = 0; i < 4; ++i) {
            int r = q4 * 4 + i;
            #pragma unroll
            for (int ct = 0; ct < 4; ++ct)
                Axl[s][r * ASTR + wave * 64 + ct * 16 + l16] = f2b(acc[ct][i]);
        }
        __syncthreads();  // B1: park visible

        // epilogue partial: comb += g_s * (s==0 ? y : LN(q+y))
        if (s == 0) {
            #pragma unroll
            for (int rr = 0; rr < 4; ++rr) {
                int r = wave * 4 + rr;
                uint2 u = *(const uint2*)(&Axl[s][r * ASTR + j]);
                float y0 = b2f(u.x & 0xffff) + bfv.x, y1 = b2f(u.x >> 16) + bfv.y;
                float y2 = b2f(u.y & 0xffff) + bfv.z, y3 = b2f(u.y >> 16) + bfv.w;
                float g0 = gLDS[r * 8 + 0];
                comb[rr][0] += g0 * y0; comb[rr][1] += g0 * y1;
                comb[rr][2] += g0 * y2; comb[rr][3] += g0 * y3;
            }
        } else {
            #pragma unroll
            for (int rr = 0; rr < 4; ++rr) {
                int r = wave * 4 + rr;
                uint2 u = *(const uint2*)(&Axl[s][r * ASTR + j]);
                float t0 = qv[rr][0] + b2f(u.x & 0xffff) + bfv.x;
                float t1 = qv[rr][1] + b2f(u.x >> 16)    + bfv.y;
                float t2 = qv[rr][2] + b2f(u.y & 0xffff) + bfv.z;
                float t3 = qv[rr][3] + b2f(u.y >> 16)    + bfv.w;
                float s1 = wred(t0 + t1 + t2 + t3);
                float s2 = wred(t0*t0 + t1*t1 + t2*t2 + t3*t3);
                float mn = s1 * (1.f / 256.f);
                float vr = s2 * (1.f / 256.f) - mn * mn;
                float rs = rsqrtf(vr + 1e-5f);
                float gs = gLDS[r * 8 + s];
                comb[rr][0] += gs * ((t0 - mn) * rs * cg.x + cb.x);
                comb[rr][1] += gs * ((t1 - mn) * rs * cg.y + cb.y);
                comb[rr][2] += gs * ((t2 - mn) * rs * cg.z + cb.z);
                comb[rr][3] += gs * ((t3 - mn) * rs * cg.w + cb.w);
            }
        }
        // no barrier needed here: next iteration touches only Axl[s+1]
    }

    // final LN and store (float4-coalesced)
    float4 fg = *(const float4*)(fln_g + j);
    float4 fb = *(const float4*)(fln_b + j);
    #pragma unroll
    for (int rr = 0; rr < 4; ++rr) {
        int r = wave * 4 + rr;
        float t0 = qv[rr][0] + comb[rr][0], t1 = qv[rr][1] + comb[rr][1];
        float t2 = qv[rr][2] + comb[rr][2], t3 = qv[rr][3] + comb[rr][3];
        float s1 = wred(t0 + t1 + t2 + t3);
        float s2 = wred(t0*t0 + t1*t1 + t2*t2 + t3*t3);
        float mn = s1 * (1.f / 256.f);
        float vr = s2 * (1.f / 256.f) - mn * mn;
        float rs = rsqrtf(vr + 1e-5f);
        float4 ov;
        ov.x = (t0 - mn) * rs * fg.x + fb.x;
        ov.y = (t1 - mn) * rs * fg.y + fb.y;
        ov.z = (t2 - mn) * rs * fg.z + fb.z;
        ov.w = (t3 - mn) * rs * fg.w + fb.w;
        *(float4*)(out + (size_t)(b0 + r) * 256 + j) = ov;
    }
}

extern "C" void kernel_launch(void* const* d_in, const int* in_sizes, int n_in,
                              void* d_out, int out_size, void* d_ws, size_t ws_size,
                              hipStream_t stream) {
    const float* x    = (const float*)d_in[0];
    const float* sWi  = (const float*)d_in[1];
    const float* sbi  = (const float*)d_in[2];
    const float* sWo  = (const float*)d_in[3];
    const float* sbo  = (const float*)d_in[4];
    const float* cWi  = (const float*)d_in[5];
    const float* cbi  = (const float*)d_in[6];
    const float* cWo  = (const float*)d_in[7];
    const float* cbo  = (const float*)d_in[8];
    const float* clng = (const float*)d_in[9];
    const float* clnb = (const float*)d_in[10];
    const float* glng = (const float*)d_in[11];
    const float* glnb = (const float*)d_in[12];
    const float* gW   = (const float*)d_in[13];
    const float* gb   = (const float*)d_in[14];
    const float* flng = (const float*)d_in[15];
    const float* flnb = (const float*)d_in[16];
    const int* midx   = (const int*)d_in[17];
    float* out        = (float*)d_out;

    char* ws = (char*)d_ws;
    unsigned short* WT = (unsigned short*)ws;         // 5*256*256*2 = 655360 B (fragment order)
    float* BF          = (float*)(ws + 655360);       // 5*256*4 = 5120 B  (total 660480 B)

    k_fuse<<<dim3(64, 5), 256, 0, stream>>>(sWi, sbi, sWo, sbo, cWi, cbi, cWo, cbo, WT, BF);
    k_main<<<1024, 256, 0, stream>>>(x, WT, BF, clng, clnb, glng, glnb, gW, gb, flng, flnb, midx, out);
}